// Round 2
// baseline (624.761 us; speedup 1.0000x reference)
//
#include <hip/hip_runtime.h>
#include <hip/hip_bf16.h>
#include <stdint.h>

typedef __bf16 bf16_t;
typedef __attribute__((ext_vector_type(8))) __bf16 bf16x8;
typedef __attribute__((ext_vector_type(4))) float f32x4;

#define S_LEN 4096
#define DMODEL 1024
#define NHEADS 16
#define DKH 64

__device__ __forceinline__ f32x4 mfma16(bf16x8 a, bf16x8 b, f32x4 c) {
  return __builtin_amdgcn_mfma_f32_16x16x32_bf16(a, b, c, 0, 0, 0);
}

// Load 8 consecutive elements at g (fp32 or bf16) as bf16x8.
template <typename TS>
__device__ __forceinline__ bf16x8 load8_bf16(const TS* g) {
  bf16x8 o;
  if constexpr (sizeof(TS) == 4) {
    const float4 f0 = *(const float4*)(g);
    const float4 f1 = *(const float4*)(g + 4);
    o[0] = (bf16_t)f0.x; o[1] = (bf16_t)f0.y; o[2] = (bf16_t)f0.z; o[3] = (bf16_t)f0.w;
    o[4] = (bf16_t)f1.x; o[5] = (bf16_t)f1.y; o[6] = (bf16_t)f1.z; o[7] = (bf16_t)f1.w;
  } else {
    o = *(const bf16x8*)(g);
  }
  return o;
}

// Stage a tile whose rows are 64 elements, converting to bf16, XOR-swizzled:
// LDS[row][c] holds global chunk g = c ^ (row&7)  (chunk = 8 elements).
template <typename TS>
__device__ __forceinline__ void stage_tile64(const TS* __restrict__ g, int gstride,
                                             bf16_t* lds, int rows, int tid) {
  for (int i = tid; i < rows * 8; i += 256) {
    int row = i >> 3, c = i & 7, cg = c ^ (row & 7);
    bf16x8 v = load8_bf16(g + (size_t)row * gstride + cg * 8);
    *(bf16x8*)((char*)lds + row * 128 + c * 16) = v;
  }
}

// Read a 16B fragment (global chunk g of row) from a swizzled 64-elem-row tile.
__device__ __forceinline__ bf16x8 frag64(const bf16_t* lds, int row, int g) {
  return *(const bf16x8*)((const char*)lds + row * 128 + ((g ^ (row & 7)) * 16));
}

// ---------------- transpose+convert: dst[c][r] = (bf16)src[r][c], 64x64 tiles ----------------
template <typename TS>
__global__ __launch_bounds__(256) void transpose_to_bf16(const TS* __restrict__ src, int srcStride,
                                                         bf16_t* __restrict__ dst, int dstStride) {
  __shared__ bf16_t t[64][65];
  const int tid = threadIdx.x;
  const int r0 = blockIdx.y * 64, c0 = blockIdx.x * 64;
#pragma unroll
  for (int it = 0; it < 2; ++it) {
    int idx = tid + it * 256;
    int r = idx >> 3, c8 = idx & 7;
    bf16x8 v = load8_bf16(src + (size_t)(r0 + r) * srcStride + c0 + c8 * 8);
#pragma unroll
    for (int j = 0; j < 8; ++j) t[c8 * 8 + j][r] = v[j];
  }
  __syncthreads();
#pragma unroll
  for (int it = 0; it < 2; ++it) {
    int idx = tid + it * 256;
    int r = idx >> 3, c8 = idx & 7;
    bf16x8 v;
#pragma unroll
    for (int j = 0; j < 8; ++j) v[j] = t[r][c8 * 8 + j];
    *(bf16x8*)(dst + (size_t)(c0 + r) * dstStride + r0 + c8 * 8) = v;
  }
}

// ---------------- NT GEMM: C[M][N] = (bf16)A[M][K] * Bt[N][K]^T + bias ----------------
template <int BN, typename TA, typename TC>
__global__ __launch_bounds__(256) void gemm_nt(const TA* __restrict__ A, int lda,
                                               const bf16_t* __restrict__ Bt, int ldb,
                                               const float* __restrict__ bias,
                                               TC* __restrict__ C, int ldc, int K) {
  constexpr int BM = 128;
  constexpr int RT = (BN == 128) ? 4 : 2;
  constexpr int CT = 4;
  __shared__ __align__(16) bf16_t As[BM * 64];
  __shared__ __align__(16) bf16_t Bs[BN * 64];
  const int tid = threadIdx.x, l = tid & 63, w = tid >> 6;
  const int lr = l & 15, quad = l >> 4;
  const int m0 = blockIdx.y * BM, n0 = blockIdx.x * BN;
  const int wm = (BN == 128) ? (w >> 1) * 64 : w * 32;
  const int wn = (BN == 128) ? (w & 1) * 64 : 0;

  f32x4 zero = {0.f, 0.f, 0.f, 0.f};
  f32x4 acc[RT][CT];
#pragma unroll
  for (int i = 0; i < RT; ++i)
#pragma unroll
    for (int j = 0; j < CT; ++j) acc[i][j] = zero;

  const int nt = K >> 6;
  for (int t = 0; t < nt; ++t) {
    __syncthreads();
    stage_tile64(A + (size_t)m0 * lda + t * 64, lda, As, BM, tid);
    stage_tile64(Bt + (size_t)n0 * ldb + t * 64, ldb, Bs, BN, tid);
    __syncthreads();
#pragma unroll
    for (int kc = 0; kc < 2; ++kc) {
      bf16x8 af[RT], bfr[CT];
#pragma unroll
      for (int rt = 0; rt < RT; ++rt) af[rt] = frag64(As, wm + rt * 16 + lr, kc * 4 + quad);
#pragma unroll
      for (int ct = 0; ct < CT; ++ct) bfr[ct] = frag64(Bs, wn + ct * 16 + lr, kc * 4 + quad);
#pragma unroll
      for (int rt = 0; rt < RT; ++rt)
#pragma unroll
        for (int ct = 0; ct < CT; ++ct) acc[rt][ct] = mfma16(af[rt], bfr[ct], acc[rt][ct]);
    }
  }
#pragma unroll
  for (int rt = 0; rt < RT; ++rt)
#pragma unroll
    for (int ct = 0; ct < CT; ++ct) {
      const int n = n0 + wn + ct * 16 + lr;
      const float bv = bias[n];
      const int mb = m0 + wm + rt * 16 + quad * 4;
#pragma unroll
      for (int r = 0; r < 4; ++r)
        C[(size_t)(mb + r) * ldc + n] = (TC)(acc[rt][ct][r] + bv);
    }
}

// ---------------- fused flash-style MQA attention ----------------
// grid (S/128, H). qp: [S][DMODEL] (head h at cols h*64..); kv: [S][128] (kp = cols 0..63);
// vt: [64][S] (V^T). out: [S][DMODEL] at [s][h*64+d].
__global__ __launch_bounds__(256) void mqa_attn(const bf16_t* __restrict__ qp,
                                                const bf16_t* __restrict__ kv,
                                                const bf16_t* __restrict__ vt,
                                                bf16_t* __restrict__ outp) {
  __shared__ __align__(16) bf16_t Ks[128 * 64];  // 16 KB, swizzled 8-chunk rows
  __shared__ __align__(16) bf16_t Vs[64 * 128];  // 16 KB, swizzled 16-chunk rows (V^T tile)
  __shared__ __align__(16) bf16_t Ps[128 * 128]; // 32 KB, swizzled 16-chunk rows
  const int tid = threadIdx.x, l = tid & 63, w = tid >> 6;
  const int lr = l & 15, quad = l >> 4;
  const int h = blockIdx.y;
  const int q0 = blockIdx.x * 128;

  // Q fragments straight from global (read once per block).
  bf16x8 qf[2][2];
#pragma unroll
  for (int rt = 0; rt < 2; ++rt)
#pragma unroll
    for (int kc = 0; kc < 2; ++kc)
      qf[rt][kc] = *(const bf16x8*)(qp + (size_t)(q0 + w * 32 + rt * 16 + lr) * DMODEL +
                                    h * DKH + kc * 32 + quad * 8);

  f32x4 zero = {0.f, 0.f, 0.f, 0.f};
  f32x4 o[2][4];
  float mi[2][4], li[2][4];
#pragma unroll
  for (int rt = 0; rt < 2; ++rt) {
#pragma unroll
    for (int cd = 0; cd < 4; ++cd) o[rt][cd] = zero;
#pragma unroll
    for (int rg = 0; rg < 4; ++rg) { mi[rt][rg] = -1e30f; li[rt][rg] = 0.f; }
  }

  for (int t = 0; t < S_LEN / 128; ++t) {
    const int key0 = t * 128;
    __syncthreads();  // prior iteration's readers of Ks/Vs are done
    stage_tile64(kv + (size_t)key0 * 128, 128, Ks, 128, tid);
    for (int i = tid; i < 64 * 16; i += 256) {  // stage V^T tile [64][128], swizzled
      int row = i >> 4, c = i & 15;
      int g = (c & 8) | ((c ^ row) & 7);
      uint4 v = *(const uint4*)(vt + (size_t)row * S_LEN + key0 + g * 8);
      *(uint4*)((char*)Vs + row * 256 + c * 16) = v;
    }
    __syncthreads();

    // S = Q K^T  (16x16 tiles; wave w owns q rows w*32..w*32+31)
    f32x4 s[2][8];
#pragma unroll
    for (int ct = 0; ct < 8; ++ct) {
      bf16x8 k0 = frag64(Ks, ct * 16 + lr, quad);
      bf16x8 k1 = frag64(Ks, ct * 16 + lr, 4 + quad);
#pragma unroll
      for (int rt = 0; rt < 2; ++rt) {
        f32x4 a = zero;
        a = mfma16(qf[rt][0], k0, a);
        a = mfma16(qf[rt][1], k1, a);
        s[rt][ct] = a;
      }
    }

    // online softmax (rows live across 16 lanes of a quad)
#pragma unroll
    for (int rt = 0; rt < 2; ++rt)
#pragma unroll
      for (int rg = 0; rg < 4; ++rg) {
        float mx = s[rt][0][rg];
#pragma unroll
        for (int ct = 1; ct < 8; ++ct) mx = fmaxf(mx, s[rt][ct][rg]);
#pragma unroll
        for (int d = 1; d < 16; d <<= 1) mx = fmaxf(mx, __shfl_xor(mx, d, 64));
        const float mnew = fmaxf(mi[rt][rg], mx);
        const float alpha = __expf(mi[rt][rg] - mnew);
        mi[rt][rg] = mnew;
        float rs = 0.f;
#pragma unroll
        for (int ct = 0; ct < 8; ++ct) {
          float p = __expf(s[rt][ct][rg] - mnew);
          s[rt][ct][rg] = p;
          rs += p;
        }
#pragma unroll
        for (int d = 1; d < 16; d <<= 1) rs += __shfl_xor(rs, d, 64);
        li[rt][rg] = li[rt][rg] * alpha + rs;
#pragma unroll
        for (int cd = 0; cd < 4; ++cd) o[rt][cd][rg] *= alpha;
      }

    // write P (C-layout -> swizzled LDS [row][col]); each wave writes only its own rows
#pragma unroll
    for (int rt = 0; rt < 2; ++rt)
#pragma unroll
      for (int ct = 0; ct < 8; ++ct) {
        const int col = ct * 16 + lr;
        const int gch = col >> 3;
#pragma unroll
        for (int rg = 0; rg < 4; ++rg) {
          const int row = w * 32 + rt * 16 + quad * 4 + rg;
          const int sc = (gch & 8) | ((gch ^ row) & 7);
          *(bf16_t*)((char*)Ps + row * 256 + sc * 16 + (col & 7) * 2) = (bf16_t)s[rt][ct][rg];
        }
      }
    // waves only read their OWN P rows -> wave-local LDS drain suffices (no 3rd barrier)
    asm volatile("s_waitcnt lgkmcnt(0)" ::: "memory");

    // O += P V  (A = P rows from LDS, B = V^T rows from LDS)
#pragma unroll
    for (int kc2 = 0; kc2 < 4; ++kc2) {
      bf16x8 pf[2];
#pragma unroll
      for (int rt = 0; rt < 2; ++rt) {
        const int row = w * 32 + rt * 16 + lr;
        const int g = kc2 * 4 + quad;
        const int sc = (g & 8) | ((g ^ row) & 7);
        pf[rt] = *(const bf16x8*)((const char*)Ps + row * 256 + sc * 16);
      }
#pragma unroll
      for (int cd = 0; cd < 4; ++cd) {
        const int vrow = cd * 16 + lr;
        const int g = kc2 * 4 + quad;
        const int sc = (g & 8) | ((g ^ vrow) & 7);
        bf16x8 vf = *(const bf16x8*)((const char*)Vs + vrow * 256 + sc * 16);
#pragma unroll
        for (int rt = 0; rt < 2; ++rt) o[rt][cd] = mfma16(pf[rt], vf, o[rt][cd]);
      }
    }
  }

  // epilogue: O / l, write [s][h*64+d]
#pragma unroll
  for (int rt = 0; rt < 2; ++rt)
#pragma unroll
    for (int cd = 0; cd < 4; ++cd)
#pragma unroll
      for (int rg = 0; rg < 4; ++rg) {
        const int row = q0 + w * 32 + rt * 16 + quad * 4 + rg;
        const int colg = h * DKH + cd * 16 + lr;
        outp[(size_t)row * DMODEL + colg] = (bf16_t)(o[rt][cd][rg] / li[rt][rg]);
      }
}

extern "C" void kernel_launch(void* const* d_in, const int* in_sizes, int n_in,
                              void* d_out, int out_size, void* d_ws, size_t ws_size,
                              hipStream_t stream) {
  const float* q  = (const float*)d_in[0];
  const float* k  = (const float*)d_in[1];
  const float* v  = (const float*)d_in[2];
  const float* Wq = (const float*)d_in[3];
  const float* bq = (const float*)d_in[4];
  const float* Wk = (const float*)d_in[5];
  const float* bk = (const float*)d_in[6];
  const float* Wv = (const float*)d_in[7];
  const float* bv = (const float*)d_in[8];
  const float* Wo = (const float*)d_in[9];
  const float* bo = (const float*)d_in[10];
  float* out = (float*)d_out;
  char* ws = (char*)d_ws;

  bf16_t* Wqt  = (bf16_t*)(ws);                        // 1024x1024 (2 MB)
  bf16_t* Wot  = (bf16_t*)(ws + (size_t)(2u << 20));   // 1024x1024 (2 MB)
  bf16_t* Wkt  = (bf16_t*)(ws + (size_t)(4u << 20));   // 64x1024 (128 KB)
  bf16_t* Wvt  = (bf16_t*)(ws + (size_t)(4u << 20) + 131072);
  bf16_t* qp   = (bf16_t*)(ws + (size_t)(5u << 20));   // 4096x1024 (8 MB)
  bf16_t* kvb  = (bf16_t*)(ws + (size_t)(13u << 20));  // 4096x128 (1 MB): kp|vp
  bf16_t* vtb  = (bf16_t*)(ws + (size_t)(14u << 20));  // 64x4096 (512 KB)
  bf16_t* attn = (bf16_t*)(ws + (size_t)(15u << 20));  // 4096x1024 (8 MB)

  dim3 B(256);
  transpose_to_bf16<float><<<dim3(16, 16), B, 0, stream>>>(Wq, 1024, Wqt, 1024);
  transpose_to_bf16<float><<<dim3(1, 16), B, 0, stream>>>(Wk, 64, Wkt, 1024);
  transpose_to_bf16<float><<<dim3(1, 16), B, 0, stream>>>(Wv, 64, Wvt, 1024);
  transpose_to_bf16<float><<<dim3(16, 16), B, 0, stream>>>(Wo, 1024, Wot, 1024);

  gemm_nt<128, float, bf16_t><<<dim3(8, 32), B, 0, stream>>>(q, 1024, Wqt, 1024, bq, qp, 1024, 1024);
  gemm_nt<64, float, bf16_t><<<dim3(1, 32), B, 0, stream>>>(k, 1024, Wkt, 1024, bk, kvb, 128, 1024);
  gemm_nt<64, float, bf16_t><<<dim3(1, 32), B, 0, stream>>>(v, 1024, Wvt, 1024, bv, kvb + 64, 128, 1024);

  transpose_to_bf16<bf16_t><<<dim3(1, 64), B, 0, stream>>>(kvb + 64, 128, vtb, 4096);

  mqa_attn<<<dim3(32, 16), B, 0, stream>>>(qp, kvb, vtb, attn);

  gemm_nt<128, bf16_t, float><<<dim3(8, 32), B, 0, stream>>>(attn, 1024, Wot, 1024, bo, out, 1024, 1024);
}